// Round 6
// baseline (108.743 us; speedup 1.0000x reference)
//
#include <hip/hip_runtime.h>

// DRMM scoring kernel, round 6.
// Shapes: B=32, D=8, QL=16, DL=512, E=300, V=50000, 5 histogram bins.
// One block per (b,d) doc pair; 256 threads, T=2 doc tokens per lane.
// Global doc-row loads are LINE-GRANULAR: each 64B region (16 floats) is
// fetched as 4 back-to-back float4 loads into a named stage-slot, so each
// cache line is fetched once (round 4's per-float4 walk thrashed L1: 512
// tokens x 64B live lines = 32KB = L1 size, so the 4 same-line accesses
// separated by whole chunk iterations each re-missed).
// Two stage-slots, reload-in-place, loop unrolled x2 (no rotation, no
// branches, no index math) -- the round-4 idiom that the compiler schedules
// well. Reload distance = 2 stages (~1100 issue-cycles of FMA cover).
// q-chunk reads stay just-in-time from LDS (broadcast reads, ~4cyc, cheap).
// Per-token dot/norm summation order is bit-identical to rounds 1-5.

constexpr int Bn  = 32;
constexpr int Dn  = 8;
constexpr int QLn = 16;
constexpr int DLn = 512;
constexpr int En  = 300;

__global__ __launch_bounds__(256) void drmm_score(
    const int*   __restrict__ bq,    // [B,QL]
    const int*   __restrict__ bd,    // [B,D,DL]
    const float* __restrict__ emb,   // [V,E]
    const float* __restrict__ w_g,   // [E]
    const float* __restrict__ b_g,   // [1]
    const float* __restrict__ w1,    // [5]
    const float* __restrict__ b1,    // [1]
    const float* __restrict__ w2,    // [1]
    const float* __restrict__ b2,    // [1]
    const float* __restrict__ w_o,   // [1]
    const float* __restrict__ b_o,   // [1]
    float*       __restrict__ out)   // [B*D]
{
    __shared__ __attribute__((aligned(16))) float q_lds[QLn * En]; // 19200 B
    __shared__ float pn_s[QLn][17];
    __shared__ float pg_s[QLn][17];
    __shared__ float qn_s[QLn];
    __shared__ float gate_s[QLn];
    __shared__ float tw_s[QLn];
    __shared__ unsigned long long hist_s[QLn]; // 5 x 12-bit packed counters per q
    __shared__ float wsum_s[QLn];

    const int n   = blockIdx.x;   // 0..255  (b*8 + d)
    const int b   = n >> 3;
    const int tid = threadIdx.x;  // 0..255

    // ---- Phase 1: stage query embeddings into LDS (float4 granularity) ----
    for (int idx = tid; idx < QLn * (En / 4); idx += 256) {   // 1200 float4s
        const int  q   = idx / (En / 4);
        const int  c   = idx - q * (En / 4);
        const long tok = bq[b * QLn + q];
        *reinterpret_cast<float4*>(&q_lds[q * En + c * 4]) =
            *reinterpret_cast<const float4*>(emb + tok * (long)En + c * 4);
    }
    if (tid < QLn) hist_s[tid] = 0ull;
    __syncthreads();

    // ---- Phase 2: query norms + gate logits (16 threads per q) ----
    {
        const int q = tid >> 4, j = tid & 15;
        float pn = 0.f, pg = 0.f;
        for (int e = j; e < En; e += 16) {
            const float v = q_lds[q * En + e];
            pn = fmaf(v, v, pn);
            pg = fmaf(v, w_g[e], pg);
        }
        pn_s[q][j] = pn;
        pg_s[q][j] = pg;
    }
    __syncthreads();
    if (tid < QLn) {
        float sn = 0.f, sg = 0.f;
        for (int j = 0; j < 16; ++j) { sn += pn_s[tid][j]; sg += pg_s[tid][j]; }
        qn_s[tid]   = sqrtf(sn);
        gate_s[tid] = sg + b_g[0];
    }
    __syncthreads();
    if (tid == 0) {
        float m = gate_s[0];
        for (int q = 1; q < QLn; ++q) m = fmaxf(m, gate_s[q]);
        float ex[QLn];
        float s = 0.f;
        for (int q = 0; q < QLn; ++q) { ex[q] = expf(gate_s[q] - m); s += ex[q]; }
        for (int q = 0; q < QLn; ++q) tw_s[q] = ex[q] / s;
    }
    __syncthreads();

    // ---- Phase 3: per-token cosine sims; 2 tokens per lane ----
    const long tok0 = bd[n * DLn + tid];
    const long tok1 = bd[n * DLn + tid + 256];
    const float* __restrict__ r0 = emb + tok0 * (long)En;
    const float* __restrict__ r1 = emb + tok1 * (long)En;

    float acc0[QLn], acc1[QLn];
#pragma unroll
    for (int q = 0; q < QLn; ++q) { acc0[q] = 0.f; acc1[q] = 0.f; }
    float nr0 = 0.f, nr1 = 0.f;

    // one 4-float chunk for both tokens (order identical to rounds 1-5)
#define DRMM_CHUNK(d0, d1, EE)                                            \
    do {                                                                  \
        nr0 = fmaf((d0).x, (d0).x, nr0);                                  \
        nr0 = fmaf((d0).y, (d0).y, nr0);                                  \
        nr0 = fmaf((d0).z, (d0).z, nr0);                                  \
        nr0 = fmaf((d0).w, (d0).w, nr0);                                  \
        nr1 = fmaf((d1).x, (d1).x, nr1);                                  \
        nr1 = fmaf((d1).y, (d1).y, nr1);                                  \
        nr1 = fmaf((d1).z, (d1).z, nr1);                                  \
        nr1 = fmaf((d1).w, (d1).w, nr1);                                  \
        _Pragma("unroll")                                                 \
        for (int q = 0; q < QLn; ++q) {                                   \
            const float4 qv =                                             \
                *reinterpret_cast<const float4*>(&q_lds[q * En + (EE)]);  \
            float s0 = acc0[q];                                           \
            s0 = fmaf((d0).x, qv.x, s0);                                  \
            s0 = fmaf((d0).y, qv.y, s0);                                  \
            s0 = fmaf((d0).z, qv.z, s0);                                  \
            s0 = fmaf((d0).w, qv.w, s0);                                  \
            acc0[q] = s0;                                                 \
            float s1 = acc1[q];                                           \
            s1 = fmaf((d1).x, qv.x, s1);                                  \
            s1 = fmaf((d1).y, qv.y, s1);                                  \
            s1 = fmaf((d1).z, qv.z, s1);                                  \
            s1 = fmaf((d1).w, qv.w, s1);                                  \
            acc1[q] = s1;                                                 \
        }                                                                 \
    } while (0)

    // compute one 16-float stage (4 chunks) from a named slot
#define DRMM_STAGE(A0, A1, A2, A3, B0, B1, B2, B3, EE)                    \
    do {                                                                  \
        DRMM_CHUNK(A0, B0, (EE) + 0);                                     \
        DRMM_CHUNK(A1, B1, (EE) + 4);                                     \
        DRMM_CHUNK(A2, B2, (EE) + 8);                                     \
        DRMM_CHUNK(A3, B3, (EE) + 12);                                    \
    } while (0)

    // reload a slot with the stage at float-offset EE (4 back-to-back float4
    // per token -> same-64B-region accesses are co-in-flight, line fetched once)
#define DRMM_LOAD_STAGE(A0, A1, A2, A3, B0, B1, B2, B3, EE)               \
    do {                                                                  \
        A0 = *reinterpret_cast<const float4*>(r0 + (EE) + 0);             \
        A1 = *reinterpret_cast<const float4*>(r0 + (EE) + 4);             \
        A2 = *reinterpret_cast<const float4*>(r0 + (EE) + 8);             \
        A3 = *reinterpret_cast<const float4*>(r0 + (EE) + 12);            \
        B0 = *reinterpret_cast<const float4*>(r1 + (EE) + 0);             \
        B1 = *reinterpret_cast<const float4*>(r1 + (EE) + 4);             \
        B2 = *reinterpret_cast<const float4*>(r1 + (EE) + 8);             \
        B3 = *reinterpret_cast<const float4*>(r1 + (EE) + 12);            \
    } while (0)

    // prologue: slot0 = stage 0 (e=0..15), slot1 = stage 1 (e=16..31)
    float4 A00, A01, A02, A03, B00, B01, B02, B03;   // slot 0
    float4 A10, A11, A12, A13, B10, B11, B12, B13;   // slot 1
    DRMM_LOAD_STAGE(A00, A01, A02, A03, B00, B01, B02, B03, 0);
    DRMM_LOAD_STAGE(A10, A11, A12, A13, B10, B11, B12, B13, 16);

    // stages 0..15 computed, stages 2..17 reloaded (distance = 2 stages)
#pragma unroll 1
    for (int k = 0; k < 8; ++k) {
        const int e0 = k * 32;
        DRMM_STAGE(A00, A01, A02, A03, B00, B01, B02, B03, e0);
        DRMM_LOAD_STAGE(A00, A01, A02, A03, B00, B01, B02, B03, e0 + 32);
        DRMM_STAGE(A10, A11, A12, A13, B10, B11, B12, B13, e0 + 16);
        DRMM_LOAD_STAGE(A10, A11, A12, A13, B10, B11, B12, B13, e0 + 48);
    }
    // epilogue: stage 16 (slot0), then load the 12-float tail into slot0,
    // stage 17 (slot1), tail chunks 288/292/296.
    DRMM_STAGE(A00, A01, A02, A03, B00, B01, B02, B03, 256);
    A00 = *reinterpret_cast<const float4*>(r0 + 288);
    A01 = *reinterpret_cast<const float4*>(r0 + 292);
    A02 = *reinterpret_cast<const float4*>(r0 + 296);
    B00 = *reinterpret_cast<const float4*>(r1 + 288);
    B01 = *reinterpret_cast<const float4*>(r1 + 292);
    B02 = *reinterpret_cast<const float4*>(r1 + 296);
    DRMM_STAGE(A10, A11, A12, A13, B10, B11, B12, B13, 272);
    DRMM_CHUNK(A00, B00, 288);
    DRMM_CHUNK(A01, B01, 292);
    DRMM_CHUNK(A02, B02, 296);
#undef DRMM_LOAD_STAGE
#undef DRMM_STAGE
#undef DRMM_CHUNK

    const float dn0 = sqrtf(nr0);
    const float dn1 = sqrtf(nr1);

    unsigned long long cnt[QLn];
#pragma unroll
    for (int q = 0; q < QLn; ++q) {
        unsigned long long v = 0ull;
        {
            const float denom = fmaxf(qn_s[q] * dn0, 1e-8f);
            const float c     = acc0[q] / denom;
            int bin = -1;
            if      (c >= -1.0f && c < -0.5f) bin = 0;
            else if (c >= -0.5f && c <  0.0f) bin = 1;
            else if (c >=  0.0f && c <  0.5f) bin = 2;
            else if (c >=  0.5f && c <  1.0f) bin = 3;
            else if (c ==  1.0f)              bin = 4;
            if (bin >= 0) v += 1ull << (12 * bin);
        }
        {
            const float denom = fmaxf(qn_s[q] * dn1, 1e-8f);
            const float c     = acc1[q] / denom;
            int bin = -1;
            if      (c >= -1.0f && c < -0.5f) bin = 0;
            else if (c >= -0.5f && c <  0.0f) bin = 1;
            else if (c >=  0.0f && c <  0.5f) bin = 2;
            else if (c >=  0.5f && c <  1.0f) bin = 3;
            else if (c ==  1.0f)              bin = 4;
            if (bin >= 0) v += 1ull << (12 * bin);
        }
        cnt[q] = v;
    }

    const int lane = tid & 63;
#pragma unroll
    for (int q = 0; q < QLn; ++q) {
        unsigned long long v = cnt[q];
        for (int off = 32; off > 0; off >>= 1) v += __shfl_down(v, off, 64);
        if (lane == 0) atomicAdd(&hist_s[q], v);
    }
    __syncthreads();

    // ---- Phase 4: ffnn + gated sum -> score ----
    if (tid < QLn) {
        const unsigned long long h = hist_s[tid];
        float f = 0.f;
        f = fmaf((float)((h >>  0) & 0xFFFull), w1[0], f);
        f = fmaf((float)((h >> 12) & 0xFFFull), w1[1], f);
        f = fmaf((float)((h >> 24) & 0xFFFull), w1[2], f);
        f = fmaf((float)((h >> 36) & 0xFFFull), w1[3], f);
        f = fmaf((float)((h >> 48) & 0xFFFull), w1[4], f);
        f += b1[0];
        f = f * w2[0] + b2[0];
        wsum_s[tid] = f * tw_s[tid];
    }
    __syncthreads();
    if (tid == 0) {
        float s = 0.f;
        for (int q = 0; q < QLn; ++q) s += wsum_s[q];
        out[n] = s * w_o[0] + b_o[0];
    }
}

extern "C" void kernel_launch(void* const* d_in, const int* in_sizes, int n_in,
                              void* d_out, int out_size, void* d_ws, size_t ws_size,
                              hipStream_t stream) {
    const int*   bq  = (const int*)  d_in[0];  // batch_queries
    // d_in[1] query_len: unused by reference
    const int*   bd  = (const int*)  d_in[2];  // batch_docs
    // d_in[3] doc_len: unused by reference
    const float* emb = (const float*)d_in[4];
    const float* w_g = (const float*)d_in[5];
    const float* b_g = (const float*)d_in[6];
    const float* w1  = (const float*)d_in[7];
    const float* b1  = (const float*)d_in[8];
    const float* w2  = (const float*)d_in[9];
    const float* b2  = (const float*)d_in[10];
    const float* w_o = (const float*)d_in[11];
    const float* b_o = (const float*)d_in[12];

    drmm_score<<<Bn * Dn, 256, 0, stream>>>(
        bq, bd, emb, w_g, b_g, w1, b1, w2, b2, w_o, b_o, (float*)d_out);
}

// Round 7
// 89.467 us; speedup vs baseline: 1.2155x; 1.2155x over previous
//
#include <hip/hip_runtime.h>

// DRMM scoring kernel, round 7.
// Shapes: B=32, D=8, QL=16, DL=512, E=300, V=50000, 5 histogram bins.
// One block per (b,d) doc pair; 512 threads, T=1 doc token per lane
// (2 waves/SIMD so scalar/vector waits are covered by the co-resident wave).
// KEY CHANGE vs round 4: query-term operands come from SGPRs, not LDS.
// Token ids are made provably wave-uniform via readfirstlane, so q-chunk
// reads `emb[utok*300+e]` have uniform invariant addresses -> compiler
// selects s_load_dwordx4 into SGPRs; v_fmac_f32 takes the SGPR directly
// (1 SGPR read per VALU instr is legal). This removes all 1200 main-loop
// ds_read_b128 per token and moves q traffic to the idle scalar pipe.
// Doc rows keep round 4's proven depth-5 reload-in-place float4 slot
// pipeline (T=1 -> only 20 slot VGPRs; no spill).
// Per-token dot/norm summation order is bit-identical to rounds 1-6.

constexpr int Bn  = 32;
constexpr int Dn  = 8;
constexpr int QLn = 16;
constexpr int DLn = 512;
constexpr int En  = 300;

__global__ __launch_bounds__(512) void drmm_score(
    const int*   __restrict__ bq,    // [B,QL]
    const int*   __restrict__ bd,    // [B,D,DL]
    const float* __restrict__ emb,   // [V,E]
    const float* __restrict__ w_g,   // [E]
    const float* __restrict__ b_g,   // [1]
    const float* __restrict__ w1,    // [5]
    const float* __restrict__ b1,    // [1]
    const float* __restrict__ w2,    // [1]
    const float* __restrict__ b2,    // [1]
    const float* __restrict__ w_o,   // [1]
    const float* __restrict__ b_o,   // [1]
    float*       __restrict__ out)   // [B*D]
{
    __shared__ __attribute__((aligned(16))) float q_lds[QLn * En]; // 19200 B
    __shared__ float pn_s[QLn][17];
    __shared__ float pg_s[QLn][17];
    __shared__ float qn_s[QLn];
    __shared__ float gate_s[QLn];
    __shared__ float tw_s[QLn];
    __shared__ unsigned long long hist_s[QLn]; // 5 x 12-bit packed counters per q
    __shared__ float wsum_s[QLn];

    const int n   = blockIdx.x;   // 0..255  (b*8 + d)
    const int b   = n >> 3;
    const int tid = threadIdx.x;  // 0..511

    // ---- Phase 1: stage query embeddings into LDS (for phase 2 only) ----
    for (int idx = tid; idx < QLn * (En / 4); idx += 512) {   // 1200 float4s
        const int  q   = idx / (En / 4);
        const int  c   = idx - q * (En / 4);
        const long tok = bq[b * QLn + q];
        *reinterpret_cast<float4*>(&q_lds[q * En + c * 4]) =
            *reinterpret_cast<const float4*>(emb + tok * (long)En + c * 4);
    }
    if (tid < QLn) hist_s[tid] = 0ull;
    __syncthreads();

    // ---- Phase 2: query norms + gate logits (16 threads per q) ----
    if (tid < 256) {
        const int q = tid >> 4, j = tid & 15;
        float pn = 0.f, pg = 0.f;
        for (int e = j; e < En; e += 16) {
            const float v = q_lds[q * En + e];
            pn = fmaf(v, v, pn);
            pg = fmaf(v, w_g[e], pg);
        }
        pn_s[q][j] = pn;
        pg_s[q][j] = pg;
    }
    __syncthreads();
    if (tid < QLn) {
        float sn = 0.f, sg = 0.f;
        for (int j = 0; j < 16; ++j) { sn += pn_s[tid][j]; sg += pg_s[tid][j]; }
        qn_s[tid]   = sqrtf(sn);
        gate_s[tid] = sg + b_g[0];
    }
    __syncthreads();
    if (tid == 0) {
        float m = gate_s[0];
        for (int q = 1; q < QLn; ++q) m = fmaxf(m, gate_s[q]);
        float ex[QLn];
        float s = 0.f;
        for (int q = 0; q < QLn; ++q) { ex[q] = expf(gate_s[q] - m); s += ex[q]; }
        for (int q = 0; q < QLn; ++q) tw_s[q] = ex[q] / s;
    }
    __syncthreads();

    // ---- wave-uniform query-row pointers (scalar path) ----
    const float* __restrict__ qp[QLn];
#pragma unroll
    for (int q = 0; q < QLn; ++q) {
        const int utok = __builtin_amdgcn_readfirstlane(bq[b * QLn + q]);
        qp[q] = emb + (long)utok * En;
    }

    // ---- Phase 3: per-token cosine sims vs all 16 query terms ----
    const long tok = bd[n * DLn + tid];
    const float* __restrict__ r0 = emb + tok * (long)En;

    float acc[QLn];
#pragma unroll
    for (int q = 0; q < QLn; ++q) acc[q] = 0.f;
    float nrm = 0.f;

    // one 4-float chunk: norm FMAs then q0..q15 (order identical rounds 1-6);
    // q operands read directly from global with uniform address -> s_load.
#define DRMM_CHUNK(dv, EE)                                                \
    do {                                                                  \
        nrm = fmaf((dv).x, (dv).x, nrm);                                  \
        nrm = fmaf((dv).y, (dv).y, nrm);                                  \
        nrm = fmaf((dv).z, (dv).z, nrm);                                  \
        nrm = fmaf((dv).w, (dv).w, nrm);                                  \
        _Pragma("unroll")                                                 \
        for (int q = 0; q < QLn; ++q) {                                   \
            const float4 qv =                                             \
                *reinterpret_cast<const float4*>(qp[q] + (EE));           \
            float a = acc[q];                                             \
            a = fmaf((dv).x, qv.x, a);                                    \
            a = fmaf((dv).y, qv.y, a);                                    \
            a = fmaf((dv).z, qv.z, a);                                    \
            a = fmaf((dv).w, qv.w, a);                                    \
            acc[q] = a;                                                   \
        }                                                                 \
    } while (0)

    // compute slot's chunk, then reload the SAME slot from 5 chunks ahead
#define DRMM_STEP_R(SA, EE)                                               \
    do {                                                                  \
        DRMM_CHUNK(SA, (EE));                                             \
        SA = *reinterpret_cast<const float4*>(r0 + (EE) + 20);            \
    } while (0)

    // prologue: slots hold chunks 0..4 (5 loads in flight)
    float4 sa = *reinterpret_cast<const float4*>(r0 + 0);
    float4 sb = *reinterpret_cast<const float4*>(r0 + 4);
    float4 sc = *reinterpret_cast<const float4*>(r0 + 8);
    float4 sd = *reinterpret_cast<const float4*>(r0 + 12);
    float4 se = *reinterpret_cast<const float4*>(r0 + 16);

#pragma unroll 1
    for (int k = 0; k < 14; ++k) {          // chunks 0..69, reload 5..74
        const int e = k * 20;
        DRMM_STEP_R(sa, e + 0);
        DRMM_STEP_R(sb, e + 4);
        DRMM_STEP_R(sc, e + 8);
        DRMM_STEP_R(sd, e + 12);
        DRMM_STEP_R(se, e + 16);
    }
    // epilogue: chunks 70..74, no reload
    DRMM_CHUNK(sa, 280);
    DRMM_CHUNK(sb, 284);
    DRMM_CHUNK(sc, 288);
    DRMM_CHUNK(sd, 292);
    DRMM_CHUNK(se, 296);
#undef DRMM_STEP_R
#undef DRMM_CHUNK

    const float dn = sqrtf(nrm);
    unsigned long long cnt[QLn];
#pragma unroll
    for (int q = 0; q < QLn; ++q) {
        const float denom = fmaxf(qn_s[q] * dn, 1e-8f);
        const float c     = acc[q] / denom;
        // numpy.histogram semantics with edges [-1,-0.5,0,0.5,1,1]:
        // first 4 bins half-open [lo,hi), last bin closed [1.0,1.0].
        int bin = -1;
        if      (c >= -1.0f && c < -0.5f) bin = 0;
        else if (c >= -0.5f && c <  0.0f) bin = 1;
        else if (c >=  0.0f && c <  0.5f) bin = 2;
        else if (c >=  0.5f && c <  1.0f) bin = 3;
        else if (c ==  1.0f)              bin = 4;
        cnt[q] = (bin >= 0) ? (1ull << (12 * bin)) : 0ull;
    }

    // wave reduce the packed counters, then one LDS atomic per wave per q
    const int lane = tid & 63;
#pragma unroll
    for (int q = 0; q < QLn; ++q) {
        unsigned long long v = cnt[q];
        for (int off = 32; off > 0; off >>= 1) v += __shfl_down(v, off, 64);
        if (lane == 0) atomicAdd(&hist_s[q], v);
    }
    __syncthreads();

    // ---- Phase 4: ffnn + gated sum -> score ----
    if (tid < QLn) {
        const unsigned long long h = hist_s[tid];
        float f = 0.f;
        f = fmaf((float)((h >>  0) & 0xFFFull), w1[0], f);
        f = fmaf((float)((h >> 12) & 0xFFFull), w1[1], f);
        f = fmaf((float)((h >> 24) & 0xFFFull), w1[2], f);
        f = fmaf((float)((h >> 36) & 0xFFFull), w1[3], f);
        f = fmaf((float)((h >> 48) & 0xFFFull), w1[4], f);
        f += b1[0];
        f = f * w2[0] + b2[0];
        wsum_s[tid] = f * tw_s[tid];
    }
    __syncthreads();
    if (tid == 0) {
        float s = 0.f;
        for (int q = 0; q < QLn; ++q) s += wsum_s[q];
        out[n] = s * w_o[0] + b_o[0];
    }
}

extern "C" void kernel_launch(void* const* d_in, const int* in_sizes, int n_in,
                              void* d_out, int out_size, void* d_ws, size_t ws_size,
                              hipStream_t stream) {
    const int*   bq  = (const int*)  d_in[0];  // batch_queries
    // d_in[1] query_len: unused by reference
    const int*   bd  = (const int*)  d_in[2];  // batch_docs
    // d_in[3] doc_len: unused by reference
    const float* emb = (const float*)d_in[4];
    const float* w_g = (const float*)d_in[5];
    const float* b_g = (const float*)d_in[6];
    const float* w1  = (const float*)d_in[7];
    const float* b1  = (const float*)d_in[8];
    const float* w2  = (const float*)d_in[9];
    const float* b2  = (const float*)d_in[10];
    const float* w_o = (const float*)d_in[11];
    const float* b_o = (const float*)d_in[12];

    drmm_score<<<Bn * Dn, 512, 0, stream>>>(
        bq, bd, emb, w_g, b_g, w1, b1, w2, b2, w_o, b_o, (float*)d_out);
}